// Round 1
// baseline (525.701 us; speedup 1.0000x reference)
//
#include <hip/hip_runtime.h>
#include <math.h>

// Izhikevich RS constants (match reference)
// A=0.02, Bz=0.2, C=-65, D=8, I_TONIC=-1, V_PEAK=30, RATE_DECAY=0.9
// MARGIN=50, ARENA_W=800, ARENA_H=600, PRECISION=[1,1,0.5,1]
//
// R4: split each agent across 2 threads (4 neurons each).
//  - VGPR target <=64 via __launch_bounds__(256,8) -> 32 waves/CU (was 16
//    at VGPR=102, which rounds into the 128-reg granule).
//  - noise/v0/u0 loads become one dwordx4 per lane with contiguous lanes
//    -> perfect 1KB/instruction coalescing (was 32B-stride half-line).
//  - 3-deep noise prefetch, fully unrolled step loop.
//  - per-agent scalars read by both lanes of a pair (merged by coalescer).
//  - rate pair-summed via __shfl_xor; per-neuron arithmetic bit-identical
//    to the previous passing kernel.

__global__ __launch_bounds__(256, 8) void spiking_fwd(
    const float* __restrict__ fish_x,
    const float* __restrict__ fish_y,
    const float* __restrict__ speed,
    const float* __restrict__ heading,
    const float* __restrict__ prev_x,
    const float* __restrict__ prev_y,
    const float* __restrict__ prev_heading,
    const float* __restrict__ pred_speed,
    const float* __restrict__ pred_hd,
    const float* __restrict__ v0,
    const float* __restrict__ u0,
    const float* __restrict__ noise,
    float* __restrict__ out,
    int Bn)
{
    __shared__ __align__(16) float sout[128 * 9];  // 128 agents/block, 4.6 KB
    const int t = threadIdx.x;
    const int g = blockIdx.x * 256 + t;
    const int b = g >> 1;       // agent index
    const int h = t & 1;        // half: 0 -> neurons 0..3, 1 -> neurons 4..7

    float r0 = 0.f, r1 = 0.f, r2 = 0.f, r3 = 0.f, r4 = 0.f,
          r5 = 0.f, r6 = 0.f, r7 = 0.f, r8 = 0.f;

    if (b < Bn) {
        const size_t off = (size_t)b * 8 + (size_t)(h << 2);
        const float4 vv4 = *(const float4*)(v0 + off);
        const float4 uu4 = *(const float4*)(u0 + off);
        const float* nbase = noise + off;
        const size_t sstride = (size_t)Bn * 8;

        // 3-deep prefetch of the strided noise slices (1KB/instr per wave)
        float4 nA = *(const float4*)(nbase);
        float4 nB = *(const float4*)(nbase + sstride);
        float4 nC = *(const float4*)(nbase + 2 * sstride);

        const float fx  = fish_x[b],  fy  = fish_y[b];
        const float spd = speed[b],   hdg = heading[b];
        const float px  = prev_x[b],  py  = prev_y[b], phd = prev_heading[b];
        const float ps  = pred_speed[b], phdd = pred_hd[b];

        const float dx = fx - px, dy = fy - py;
        const float actual_speed = sqrtf(dx * dx + dy * dy);

        // atan2(sin(hd), cos(hd)) == wrap hd to (-pi, pi]
        const float hd = hdg - phd;
        const float heading_delta = hd - 6.28318530717958648f *
                                    rintf(hd * 0.159154943091895336f);

        const float wall = fmaxf(0.0f,
            fmaxf(fmaxf((50.0f - fx) / 50.0f, (fx - 750.0f) / 50.0f),
                  fmaxf((50.0f - fy) / 50.0f, (fy - 550.0f) / 50.0f)));

        const float coll = (actual_speed < 1.0f && spd > 0.5f) ? 1.0f : 0.0f;

        float sh, ch;
        __sincosf(hdg, &sh, &ch);

        // IbT[n] = base current + I_TONIC + 140 (folded into v-update addend)
        float IbT[4];
        if (h == 0) {
            IbT[0] = actual_speed * 5.0f + 139.0f;
            IbT[1] = fmaxf(0.0f, 3.0f - actual_speed) * 3.0f + 139.0f;
            IbT[2] = (ch + 1.0f) * 3.0f + 139.0f;
            IbT[3] = (sh + 1.0f) * 3.0f + 139.0f;
        } else {
            IbT[0] = wall * 12.0f + 139.0f;
            IbT[1] = IbT[0];
            IbT[2] = coll * 15.0f + 139.0f;
            IbT[3] = IbT[2];
        }

        float v[4]    = {vv4.x, vv4.y, vv4.z, vv4.w};
        float u[4]    = {uu4.x, uu4.y, uu4.z, uu4.w};
        float rate[4] = {0.f, 0.f, 0.f, 0.f};

        #pragma unroll
        for (int s = 0; s < 10; ++s) {
            const float4 cur = nA;
            nA = nB; nB = nC;
            if (s < 7) nC = *(const float4*)(nbase + (size_t)(s + 3) * sstride);

            const float eps[4] = {cur.x, cur.y, cur.z, cur.w};
            #pragma unroll
            for (int n = 0; n < 4; ++n) {
                const float P  = fmaf(0.3f, eps[n], IbT[n]) - u[n];
                const float vv = fmaf(v[n], fmaf(0.04f, v[n], 6.0f), P);
                const float uu = fmaf(0.02f, fmaf(0.2f, vv, -u[n]), u[n]);
                const bool sp = (vv >= 30.0f);
                v[n] = sp ? -65.0f : vv;
                u[n] = sp ? (uu + 8.0f) : uu;
                rate[n] = fmaf(0.9f, rate[n], sp ? 0.1f : 0.0f);
            }
        }

        float rs = (rate[0] + rate[1]) + (rate[2] + rate[3]);
        rs += __shfl_xor(rs, 1, 64);      // pair-sum: both halves get total
        const float rate_mean = rs * 0.125f;

        const float norm_speed = fminf(1.0f, actual_speed * 0.25f);
        const float e0 = norm_speed - ps;
        const float e1 = heading_delta - phdd;

        r0 = actual_speed;
        r1 = heading_delta;
        r2 = wall;
        r3 = rate_mean;
        r4 = e0;
        r5 = e1;
        r6 = 0.5f * wall;
        r7 = coll;
        r8 = 0.5f * (e0 * e0 + e1 * e1 + (0.5f * wall) * wall + coll * coll);
    }

    // Stage [128 x 9] in LDS; pair splits the 9 stores (5 even / 4 odd).
    const int a = t >> 1;
    if (h == 0) {
        sout[a * 9 + 0] = r0;
        sout[a * 9 + 1] = r1;
        sout[a * 9 + 2] = r2;
        sout[a * 9 + 3] = r3;
        sout[a * 9 + 4] = r4;
    } else {
        sout[a * 9 + 5] = r5;
        sout[a * 9 + 6] = r6;
        sout[a * 9 + 7] = r7;
        sout[a * 9 + 8] = r8;
    }
    __syncthreads();

    // Flush 128*9 = 1152 floats = 288 float4, coalesced.
    const size_t base = (size_t)blockIdx.x * (128 * 9);
    const int remain = Bn - blockIdx.x * 128;
    if (remain >= 128) {
        float4* o4 = (float4*)(out + base);
        const float4* s4 = (const float4*)sout;
        o4[t] = s4[t];
        if (t < 32) o4[256 + t] = s4[256 + t];
    } else if (remain > 0) {
        const int nvalid = remain * 9;
        for (int i = t; i < nvalid; i += 256) out[base + i] = sout[i];
    }
}

extern "C" void kernel_launch(void* const* d_in, const int* in_sizes, int n_in,
                              void* d_out, int out_size, void* d_ws, size_t ws_size,
                              hipStream_t stream) {
    const float* fish_x       = (const float*)d_in[0];
    const float* fish_y       = (const float*)d_in[1];
    const float* speed        = (const float*)d_in[2];
    const float* heading      = (const float*)d_in[3];
    const float* prev_x       = (const float*)d_in[4];
    const float* prev_y       = (const float*)d_in[5];
    const float* prev_heading = (const float*)d_in[6];
    const float* pred_speed   = (const float*)d_in[7];
    const float* pred_hd      = (const float*)d_in[8];
    const float* v0           = (const float*)d_in[9];
    const float* u0           = (const float*)d_in[10];
    const float* noise        = (const float*)d_in[11];
    float* out = (float*)d_out;

    int Bn = in_sizes[0];
    int grid = (Bn + 127) / 128;   // 2 threads per agent, 128 agents/block
    spiking_fwd<<<grid, 256, 0, stream>>>(
        fish_x, fish_y, speed, heading, prev_x, prev_y, prev_heading,
        pred_speed, pred_hd, v0, u0, noise, out, Bn);
}